// Round 1
// baseline (2227.315 us; speedup 1.0000x reference)
//
#include <hip/hip_runtime.h>
#include <hip/hip_bf16.h>

#define DEV __device__ __forceinline__

typedef __bf16 bf16x8 __attribute__((ext_vector_type(8)));
typedef float  f32x4  __attribute__((ext_vector_type(4)));
typedef unsigned short u16;

DEV u16   f2b(float f) { __bf16 h = (__bf16)f; return __builtin_bit_cast(u16, h); }
DEV float b2f(u16 x)   { return __builtin_bit_cast(float, ((unsigned)x) << 16); }

// swizzled physical byte offset inside a [64 rows][128B] LDS tile:
// XOR the 16B-slot index with (row&7) -> conflict-free ds_read_b128 columns.
DEV int swz(int r, int o) { return r * 128 + (o ^ ((r & 7) << 4)); }

DEV void gl_lds16(const u16* g, u16* l) {
  __builtin_amdgcn_global_load_lds((const __attribute__((address_space(1))) void*)g,
                                   (__attribute__((address_space(3))) void*)l, 16, 0, 0);
}

// ---------------------------------------------------------------------------
// One GEMM core, 64x64 tile, BK=64, K=1024 fixed, 256 threads (4 waves).
// Computes D[m,e] = sum_d A[m,d]*B[e,d]  (A,B bf16 row-major, BT form)
// MODE 0: phase1 step  : D += pre[t(c-1)]; write bf16; write fp32 to outf if given
// MODE 1: phase3 step  : D += pre[t(c-1)]; write bf16, h_all fp32, out0 = h^2*sig(h)
// MODE 2: squaring     : write bf16 D and D^T
// MODE 3: pre-GEMM     : D += bias[e]; write bf16
// ---------------------------------------------------------------------------
template<int MODE>
__global__ __launch_bounds__(256) void gemm64(
    const u16* __restrict__ A, const u16* __restrict__ B,
    const u16* __restrict__ preb, const float* __restrict__ bias,
    u16* __restrict__ outb, u16* __restrict__ outbT,
    float* __restrict__ outf, float* __restrict__ out0, int c)
{
  __shared__ u16 Asl[4096], Bsl[4096];
  const int K = 1024;
  int tid = threadIdx.x, lane = tid & 63, w = tid >> 6;
  int m0 = blockIdx.y << 6, e0 = blockIdx.x << 6;
  int wrow = (w >> 1) << 5, wcol = (w & 1) << 5;

  f32x4 acc[2][2] = {};

  // staging: wave w, issue j covers LDS bytes [(w*2+j)*1024 + lane*16).
  // pre-swizzle the GLOBAL source so linear global_load_lds dest + swizzled
  // ds_read form the same involution (rule 21).
  int r0[2], co0[2];
#pragma unroll
  for (int j = 0; j < 2; ++j) {
    int p = ((w * 2 + j) << 10) + lane * 16;
    int r = p >> 7;
    int o = (p & 127) ^ ((r & 7) << 4);
    r0[j] = r; co0[j] = o >> 1;
  }

  for (int kt = 0; kt < K; kt += 64) {
    __syncthreads();
#pragma unroll
    for (int j = 0; j < 2; ++j) {
      int base = (w * 2 + j) << 10;  // bytes, wave-uniform
      gl_lds16(A + (m0 + r0[j]) * K + kt + co0[j], &Asl[base >> 1]);
      gl_lds16(B + (e0 + r0[j]) * K + kt + co0[j], &Bsl[base >> 1]);
    }
    asm volatile("s_waitcnt vmcnt(0)" ::: "memory");
    __syncthreads();
#pragma unroll
    for (int ks = 0; ks < 2; ++ks) {
      bf16x8 af[2], bfr[2];
      int oa = ks * 64 + ((lane >> 4) << 4);   // k-byte offset of this lane's 8 elems
#pragma unroll
      for (int s = 0; s < 2; ++s) {
        af[s]  = *(const bf16x8*)((const char*)Asl + swz(wrow + s * 16 + (lane & 15), oa));
        bfr[s] = *(const bf16x8*)((const char*)Bsl + swz(wcol + s * 16 + (lane & 15), oa));
      }
#pragma unroll
      for (int ms = 0; ms < 2; ++ms)
#pragma unroll
        for (int ns = 0; ns < 2; ++ns)
          acc[ms][ns] = __builtin_amdgcn_mfma_f32_16x16x32_bf16(af[ms], bfr[ns], acc[ms][ns], 0, 0, 0);
    }
  }

  int l4 = ((lane >> 4) << 2), lc = lane & 15;
#pragma unroll
  for (int ms = 0; ms < 2; ++ms)
#pragma unroll
    for (int ns = 0; ns < 2; ++ns)
#pragma unroll
      for (int j = 0; j < 4; ++j) {
        int row = m0 + wrow + ms * 16 + l4 + j;   // m (C/D: row=(lane>>4)*4+reg)
        int col = e0 + wcol + ns * 16 + lc;       // e (C/D: col=lane&15)
        float v = acc[ms][ns][j];
        if (MODE == 0) {
          int pt = ((row >> 3) << 5) + c - 1;     // pre time index = k*32 + c-1
          v += b2f(preb[(pt * 8 + (row & 7)) * 1024 + col]);
          outb[row * 1024 + col] = f2b(v);
          if (outf) outf[row * 1024 + col] = v;
        } else if (MODE == 1) {
          int pt = ((row >> 3) << 5) + c - 1;
          v += b2f(preb[(pt * 8 + (row & 7)) * 1024 + col]);
          outb[row * 1024 + col] = f2b(v);
          int t = pt + 1;                          // h index = k*32 + c
          outf[t * 8192 + (row & 7) * 1024 + col] = v;          // h_all[t]
          float sg = 1.f / (1.f + __expf(-v));
          out0[(t - 1) * 8192 + (row & 7) * 1024 + col] = v * v * sg;
        } else if (MODE == 2) {
          u16 h = f2b(v);
          outb[row * 1024 + col] = h;
          outbT[col * 1024 + row] = h;
        } else {
          v += bias[col];
          outb[row * 1024 + col] = f2b(v);
        }
      }
}

// ---- boundary chain step: bnd[k+1] = Wh^32 * bnd[k] + lC[k] -----------------
__global__ __launch_bounds__(256) void bnd_step(
    const float* __restrict__ hin, const u16* __restrict__ WhC,
    const float* __restrict__ lC, float* __restrict__ hout,
    u16* __restrict__ houtb, int k)
{
  int tid = threadIdx.x, lg = tid & 15, ei = tid >> 4;
  int e = blockIdx.x * 16 + ei;
  float accv[8] = {};
  for (int d = lg; d < 1024; d += 16) {
    float wv = b2f(WhC[e * 1024 + d]);
#pragma unroll
    for (int b = 0; b < 8; ++b) accv[b] += wv * hin[b * 1024 + d];
  }
#pragma unroll
  for (int m = 1; m < 16; m <<= 1)
#pragma unroll
    for (int b = 0; b < 8; ++b) accv[b] += __shfl_xor(accv[b], m);
  if (lg == 0) {
#pragma unroll
    for (int b = 0; b < 8; ++b) {
      float v = accv[b] + lC[(k * 8 + b) * 1024 + e];
      hout[b * 1024 + e] = v;
      if (houtb) houtb[b * 1024 + e] = f2b(v);
    }
  }
}

// ---- power iteration helpers ------------------------------------------------
__global__ void k_init(const float* __restrict__ u_in, const float* __restrict__ h0,
                       float* __restrict__ u_cur, float* __restrict__ v_acc,
                       float* __restrict__ u_acc, float* __restrict__ hall0,
                       float* __restrict__ bnd0, u16* __restrict__ bndb)
{
  int i = blockIdx.x * 256 + threadIdx.x;
  if (i < 1024) { u_cur[i] = u_in[i]; v_acc[i] = 0.f; u_acc[i] = 0.f; }
  if (i < 8192) { float h = h0[i]; hall0[i] = h; bnd0[i] = h; bndb[i] = f2b(h); }
}

// v_acc[d] += sum_{e in block} W[e,d]*u[e]
__global__ void k_v(const float* __restrict__ W, const float* __restrict__ u_cur,
                    float* __restrict__ v_acc)
{
  int d = blockIdx.x * 256 + threadIdx.x;
  int e0 = blockIdx.y * 64;
  float a = 0.f;
  for (int e = e0; e < e0 + 64; ++e) a += W[e * 1024 + d] * u_cur[e];
  atomicAdd(&v_acc[d], a);
}

// u_acc[e] += sum_{d in block} W[e,d]*v[d]
__global__ void k_u(const float* __restrict__ W, const float* __restrict__ v_cur,
                    float* __restrict__ u_acc)
{
  int lg = threadIdx.x & 15, ei = threadIdx.x >> 4;
  int e = blockIdx.y * 16 + ei;
  int d0 = blockIdx.x * 512;
  float a = 0.f;
  for (int i = 0; i < 32; ++i) { int d = d0 + lg + 16 * i; a += W[e * 1024 + d] * v_cur[d]; }
#pragma unroll
  for (int m = 1; m < 16; m <<= 1) a += __shfl_xor(a, m);
  if (lg == 0) atomicAdd(&u_acc[e], a);
}

__global__ void k_norm(const float* __restrict__ acc, float* __restrict__ outv,
                       float* __restrict__ z1)
{
  __shared__ float red[16];
  int t = threadIdx.x;
  float x = acc[t];
  float ss = x * x;
#pragma unroll
  for (int m = 1; m < 64; m <<= 1) ss += __shfl_xor(ss, m);
  if ((t & 63) == 0) red[t >> 6] = ss;
  __syncthreads();
  if (t < 64) {
    float s = (t < 16) ? red[t] : 0.f;
#pragma unroll
    for (int m = 1; m < 16; m <<= 1) s += __shfl_xor(s, m);
    if (t == 0) red[0] = s;
  }
  __syncthreads();
  float nrm = sqrtf(red[0]) + 1e-8f;
  outv[t] = x / nrm;
  z1[t] = 0.f;
}

// sigma = ss/(sqrt(ss)+eps), ss = ||W v||^2 ; scale = 0.95/(sigma+eps)
__global__ void k_sigma(const float* __restrict__ acc, float* __restrict__ scale)
{
  __shared__ float red[16];
  int t = threadIdx.x;
  float x = acc[t];
  float ss = x * x;
#pragma unroll
  for (int m = 1; m < 64; m <<= 1) ss += __shfl_xor(ss, m);
  if ((t & 63) == 0) red[t >> 6] = ss;
  __syncthreads();
  if (t < 64) {
    float s = (t < 16) ? red[t] : 0.f;
#pragma unroll
    for (int m = 1; m < 16; m <<= 1) s += __shfl_xor(s, m);
    if (t == 0) {
      float sigma = s / (sqrtf(s) + 1e-8f);
      scale[0] = 0.95f / (sigma + 1e-8f);
    }
  }
}

__global__ void k_scale(const float* __restrict__ W, const float* __restrict__ scale,
                        u16* __restrict__ wb, u16* __restrict__ wbT)
{
  int i = blockIdx.x * 256 + threadIdx.x;
  float v = W[i] * scale[0];
  u16 h = f2b(v);
  wb[i] = h;
  wbT[(i & 1023) * 1024 + (i >> 10)] = h;
}

__global__ void k_cvt(const float* __restrict__ in, u16* __restrict__ out, int n)
{
  int i = (blockIdx.x * 256 + threadIdx.x) * 4;
  if (i >= n) return;
  float4 v = *(const float4*)(in + i);
  ushort4 o;
  o.x = f2b(v.x); o.y = f2b(v.y); o.z = f2b(v.z); o.w = f2b(v.w);
  *(ushort4*)(out + i) = o;
}

// phase-1 c=1 init: l[1] = p[k*32]  (copy pre rows into l buffer, bf16)
__global__ void k_linit(const u16* __restrict__ preb, u16* __restrict__ l)
{
  int i = blockIdx.x * 256 + threadIdx.x;   // 512 blocks: 512*1024/4 ushort4
  int m = i >> 8;
  int c4 = (i & 255) * 4;
  const u16* src = preb + ((((m >> 3) << 5)) * 8 + (m & 7)) * 1024 + c4;
  *(ushort4*)(l + m * 1024 + c4) = *(const ushort4*)src;
}

extern "C" void kernel_launch(void* const* d_in, const int* in_sizes, int n_in,
                              void* d_out, int out_size, void* d_ws, size_t ws_size,
                              hipStream_t stream)
{
  (void)in_sizes; (void)n_in; (void)out_size; (void)ws_size;
  const float* x  = (const float*)d_in[0];   // [2048,8,1024]
  const float* h0 = (const float*)d_in[1];   // [8,1024]
  const float* Wx = (const float*)d_in[2];   // [1024,1024]
  const float* Wh = (const float*)d_in[3];   // [1024,1024]
  const float* bv = (const float*)d_in[4];   // [1024]
  const float* uv = (const float*)d_in[5];   // [1024]

  float* out0 = (float*)d_out;               // [2048,8,1024] h^2*sig(h)
  float* hall = out0 + 16777216;             // [2049,8,1024]

  char* ws = (char*)d_ws;
  u16*   pre_b = (u16*)(ws);                  // 32 MB  pre bf16 [2048*8,1024]
  u16*   wh_b  = (u16*)(ws + 33554432);       // 2 MB   Wh bf16
  u16*   whT_b = (u16*)(ws + 35651584);       // 2 MB   Wh^T bf16
  u16*   sA    = (u16*)(ws + 37748736);       // 2 MB   squaring ping
  u16*   sAT   = (u16*)(ws + 39845888);
  u16*   sB    = (u16*)(ws + 41943040);       // 2 MB   squaring pong (also Wx bf16)
  u16*   sBT   = (u16*)(ws + 44040192);
  float* bndf  = (float*)(ws + 46137344);     // [65,8,1024] fp32 boundaries
  u16*   bnd_b = (u16*)(ws + 48267264);       // [512,1024] bf16 boundaries
  float* lC    = (float*)(ws + 49315840);     // [512,1024] fp32 chunk-final locals
  u16*   lb0   = (u16*)(ws + 51412992);       // [512,1024] bf16 state ping
  u16*   lb1   = (u16*)(ws + 52461568);       //             state pong
  float* u_cur = (float*)(ws + 53510144);
  float* v_cur = u_cur + 1024;
  float* v_acc = u_cur + 2048;
  float* u_acc = u_cur + 3072;
  float* scale = u_cur + 4096;
  u16*   xb    = (u16*)d_out;                 // x bf16 staged in out0 region (dead before phase 3 writes)

  k_init<<<32, 256, 0, stream>>>(uv, h0, u_cur, v_acc, u_acc, hall, bndf, bnd_b);

  for (int it = 0; it < 3; ++it) {
    k_v<<<dim3(4, 16), 256, 0, stream>>>(Wh, u_cur, v_acc);
    k_norm<<<1, 1024, 0, stream>>>(v_acc, v_cur, u_acc);
    k_u<<<dim3(2, 64), 256, 0, stream>>>(Wh, v_cur, u_acc);
    if (it < 2) k_norm<<<1, 1024, 0, stream>>>(u_acc, u_cur, v_acc);
    else        k_sigma<<<1, 1024, 0, stream>>>(u_acc, scale);
  }
  k_scale<<<4096, 256, 0, stream>>>(Wh, scale, wh_b, whT_b);

  // pre = x @ Wx^T + b   (convert inputs to bf16 first; Wx bf16 parked in sB)
  k_cvt<<<16384, 256, 0, stream>>>(x, xb, 16777216);
  k_cvt<<<1024, 256, 0, stream>>>(Wx, sB, 1048576);
  gemm64<3><<<dim3(16, 256), 256, 0, stream>>>(xb, sB, nullptr, bv, pre_b, nullptr, nullptr, nullptr, 0);

  // Wh^32 by repeated squaring (A*B^T form, keep transposes)
  gemm64<2><<<dim3(16, 16), 256, 0, stream>>>(wh_b, whT_b, nullptr, nullptr, sA, sAT, nullptr, nullptr, 0);
  gemm64<2><<<dim3(16, 16), 256, 0, stream>>>(sA, sAT, nullptr, nullptr, sB, sBT, nullptr, nullptr, 0);
  gemm64<2><<<dim3(16, 16), 256, 0, stream>>>(sB, sBT, nullptr, nullptr, sA, sAT, nullptr, nullptr, 0);
  gemm64<2><<<dim3(16, 16), 256, 0, stream>>>(sA, sAT, nullptr, nullptr, sB, sBT, nullptr, nullptr, 0);
  gemm64<2><<<dim3(16, 16), 256, 0, stream>>>(sB, sBT, nullptr, nullptr, sA, sAT, nullptr, nullptr, 0);
  // WhC = sA = Wh^32

  // phase 1: local scans from zero, all 64 chunks in parallel (M=512)
  k_linit<<<512, 256, 0, stream>>>(pre_b, lb0);
  for (int c = 2; c <= 32; ++c) {
    u16* in  = (c & 1) ? lb1 : lb0;
    u16* out = (c & 1) ? lb0 : lb1;
    gemm64<0><<<dim3(16, 8), 256, 0, stream>>>(in, wh_b, pre_b, nullptr, out, nullptr,
                                               (c == 32) ? lC : nullptr, nullptr, c);
  }

  // phase 2: boundary chain, 64 sequential matvec steps
  for (int k = 0; k < 64; ++k)
    bnd_step<<<64, 256, 0, stream>>>(bndf + k * 8192, sA, lC, bndf + (k + 1) * 8192,
                                     (k < 63) ? (bnd_b + (size_t)(k + 1) * 8192) : nullptr, k);

  // phase 3: true recurrence per chunk from known boundaries; fused epilogue
  for (int c = 1; c <= 32; ++c) {
    const u16* in = (c == 1) ? bnd_b : ((c & 1) ? lb1 : lb0);
    u16* out = (c & 1) ? lb0 : lb1;
    gemm64<1><<<dim3(16, 8), 256, 0, stream>>>(in, wh_b, pre_b, nullptr, out, nullptr, hall, out0, c);
  }
}

// Round 2
// 1407.755 us; speedup vs baseline: 1.5822x; 1.5822x over previous
//
#include <hip/hip_runtime.h>
#include <hip/hip_bf16.h>

#define DEV __device__ __forceinline__

typedef __bf16 bf16x8 __attribute__((ext_vector_type(8)));
typedef float  f32x4  __attribute__((ext_vector_type(4)));
typedef unsigned short u16;

DEV u16   f2b(float f) { __bf16 h = (__bf16)f; return __builtin_bit_cast(u16, h); }
DEV float b2f(u16 x)   { return __builtin_bit_cast(float, ((unsigned)x) << 16); }

DEV void gl_lds16(const u16* g, u16* l) {
  __builtin_amdgcn_global_load_lds((const __attribute__((address_space(1))) void*)g,
                                   (__attribute__((address_space(3))) void*)l, 16, 0, 0);
}

// ---------------------------------------------------------------------------
// GEMM core, 64x64 tile, BK=128, K=1024, 256 threads (4 waves), double-buffered
// LDS with issue-early staging (min-2-phase pipeline). D[m,e] = sum_d A[m,d]*B[e,d].
// LDS tile layout: [64 rows][256 B], byte offset swizzled o ^= (row&7)<<4 on BOTH
// the pre-swizzled global source (linear global_load_lds dest) and the ds_read.
// MODE 0: phase1 step : D += pre[t(c-1)]; write bf16 (+fp32 outf if given)
// MODE 1: phase3 step : D += pre[t(c-1)]; write bf16, h_all fp32, out0=h^2*sig(h)
// MODE 2: squaring    : write bf16 D (+D^T if outbT)
// MODE 3: pre-GEMM    : D += bias[e]; write bf16
// ---------------------------------------------------------------------------
template<int MODE>
__global__ __launch_bounds__(256) void gemm64(
    const u16* __restrict__ A, const u16* __restrict__ B,
    const u16* __restrict__ preb, const float* __restrict__ bias,
    u16* __restrict__ outb, u16* __restrict__ outbT,
    float* __restrict__ outf, float* __restrict__ out0, int c)
{
  __shared__ u16 Asl[2][8192], Bsl[2][8192];   // 2 x (16KB A + 16KB B) = 64KB
  const int K = 1024;
  int tid = threadIdx.x, lane = tid & 63, w = tid >> 6;
  int m0 = blockIdx.y << 6, e0 = blockIdx.x << 6;
  int wrow = (w >> 1) << 5, wcol = (w & 1) << 5;

  f32x4 acc[2][2] = {};

  // staging precompute: wave w covers LDS bytes [w*4096,(w+1)*4096), 4 issues
  int r0[4], co0[4];
#pragma unroll
  for (int j = 0; j < 4; ++j) {
    int p = w * 4096 + j * 1024 + lane * 16;
    int r = p >> 8;                         // 256B per row
    int o = (p & 255) ^ ((r & 7) << 4);     // pre-swizzled source offset
    r0[j] = r; co0[j] = o >> 1;             // col offset in elems
  }
  auto stage = [&](int buf, int kt) {
#pragma unroll
    for (int j = 0; j < 4; ++j) {
      int base = w * 4096 + j * 1024;
      gl_lds16(A + (m0 + r0[j]) * K + kt + co0[j], &Asl[buf][base >> 1]);
      gl_lds16(B + (e0 + r0[j]) * K + kt + co0[j], &Bsl[buf][base >> 1]);
    }
  };

  stage(0, 0);
  asm volatile("s_waitcnt vmcnt(0)" ::: "memory");
  __syncthreads();

  int buf = 0;
  for (int kt = 0; kt < K; kt += 128, buf ^= 1) {
    if (kt + 128 < K) stage(buf ^ 1, kt + 128);   // issue next tile early
#pragma unroll
    for (int ks = 0; ks < 4; ++ks) {
      bf16x8 af[2], bfr[2];
      int oa = ks * 64 + ((lane >> 4) << 4);      // byte offset within 256B row
#pragma unroll
      for (int s = 0; s < 2; ++s) {
        int ra = wrow + s * 16 + (lane & 15);
        int rb = wcol + s * 16 + (lane & 15);
        af[s]  = *(const bf16x8*)((const char*)&Asl[buf][0] + ra * 256 + (oa ^ ((ra & 7) << 4)));
        bfr[s] = *(const bf16x8*)((const char*)&Bsl[buf][0] + rb * 256 + (oa ^ ((rb & 7) << 4)));
      }
#pragma unroll
      for (int ms = 0; ms < 2; ++ms)
#pragma unroll
        for (int ns = 0; ns < 2; ++ns)
          acc[ms][ns] = __builtin_amdgcn_mfma_f32_16x16x32_bf16(af[ms], bfr[ns], acc[ms][ns], 0, 0, 0);
    }
    asm volatile("s_waitcnt vmcnt(0)" ::: "memory");
    __syncthreads();
  }

  int l4 = ((lane >> 4) << 2), lc = lane & 15;
#pragma unroll
  for (int ms = 0; ms < 2; ++ms)
#pragma unroll
    for (int ns = 0; ns < 2; ++ns)
#pragma unroll
      for (int j = 0; j < 4; ++j) {
        int row = m0 + wrow + ms * 16 + l4 + j;   // C/D: row=(lane>>4)*4+reg
        int col = e0 + wcol + ns * 16 + lc;       // C/D: col=lane&15
        float v = acc[ms][ns][j];
        if (MODE == 0) {
          int pt = ((row >> 3) << 5) + c - 1;     // time = chunk*32 + c-1
          v += b2f(preb[(pt * 8 + (row & 7)) * 1024 + col]);
          outb[row * 1024 + col] = f2b(v);
          if (outf) outf[row * 1024 + col] = v;
        } else if (MODE == 1) {
          int pt = ((row >> 3) << 5) + c - 1;
          v += b2f(preb[(pt * 8 + (row & 7)) * 1024 + col]);
          outb[row * 1024 + col] = f2b(v);
          int t = pt + 1;                          // h index = chunk*32 + c
          outf[t * 8192 + (row & 7) * 1024 + col] = v;           // h_all[t]
          float sg = 1.f / (1.f + __expf(-v));
          out0[(t - 1) * 8192 + (row & 7) * 1024 + col] = v * v * sg;
        } else if (MODE == 2) {
          u16 h = f2b(v);
          outb[row * 1024 + col] = h;
          if (outbT) outbT[col * 1024 + row] = h;
        } else {
          v += bias[col];
          outb[row * 1024 + col] = f2b(v);
        }
      }
}

// ---------------------------------------------------------------------------
// Matvec chain step: hout[r,e] = sum_d W[e,d]*hin[r,d] + addv[map(r),e]
// fp32 state (no bf16 rounding of the carried chain), bf16 W (vectorized loads).
// NR=64: addv row = (r>>3)*64 + acoff*8 + (r&7); bf16 out row uses bcoff.
// NR=8 : direct row indexing (pointers pre-offset by caller).
// grid (64 e-tiles, NR/8), block 256 = 16 lanes x 16 e.
// ---------------------------------------------------------------------------
template<int NR>
__global__ __launch_bounds__(256) void matvec(
    const float* __restrict__ hin, const u16* __restrict__ W,
    const float* __restrict__ addv, float* __restrict__ hout,
    u16* __restrict__ houtb, int acoff, int bcoff)
{
  int lg = threadIdx.x & 15, eg = threadIdx.x >> 4;
  int e = blockIdx.x * 16 + eg;
  int r0 = blockIdx.y * 8;
  float acc[8] = {0,0,0,0,0,0,0,0};
  const u16* wrow = W + e * 1024;
#pragma unroll
  for (int i = 0; i < 8; ++i) {
    int d0 = lg * 8 + i * 128;
    ushort4 w0 = *(const ushort4*)(wrow + d0);
    ushort4 w1 = *(const ushort4*)(wrow + d0 + 4);
    float wa = b2f(w0.x), wb = b2f(w0.y), wc = b2f(w0.z), wd = b2f(w0.w);
    float we = b2f(w1.x), wf = b2f(w1.y), wg = b2f(w1.z), wh = b2f(w1.w);
#pragma unroll
    for (int b = 0; b < 8; ++b) {
      const float* hr = hin + (r0 + b) * 1024 + d0;
      float4 h0v = *(const float4*)hr;
      float4 h1v = *(const float4*)(hr + 4);
      acc[b] += wa*h0v.x + wb*h0v.y + wc*h0v.z + wd*h0v.w
              + we*h1v.x + wf*h1v.y + wg*h1v.z + wh*h1v.w;
    }
  }
#pragma unroll
  for (int m = 1; m < 16; m <<= 1)
#pragma unroll
    for (int b = 0; b < 8; ++b) acc[b] += __shfl_xor(acc[b], m);
  if (lg == 0) {
#pragma unroll
    for (int b = 0; b < 8; ++b) {
      int r = r0 + b;
      int ai = (NR == 64) ? (((r >> 3) << 6) + (acoff << 3) + (r & 7)) : r;
      float v = acc[b] + addv[ai * 1024 + e];
      hout[r * 1024 + e] = v;
      if (houtb) {
        int bi = (NR == 64) ? (((r >> 3) << 6) + (bcoff << 3) + (r & 7)) : r;
        houtb[bi * 1024 + e] = f2b(v);
      }
    }
  }
}

// ---- power iteration + misc helpers ----------------------------------------
__global__ void k_init(const float* __restrict__ u_in, const float* __restrict__ h0,
                       float* __restrict__ u_cur, float* __restrict__ v_acc,
                       float* __restrict__ u_acc, float* __restrict__ hall0,
                       float* __restrict__ bndS, u16* __restrict__ bndb)
{
  int i = blockIdx.x * 256 + threadIdx.x;
  if (i < 1024) { u_cur[i] = u_in[i]; v_acc[i] = 0.f; u_acc[i] = 0.f; }
  if (i < 8192) { float h = h0[i]; hall0[i] = h; bndS[i] = h; bndb[i] = f2b(h); }
}

__global__ void k_v(const float* __restrict__ W, const float* __restrict__ u_cur,
                    float* __restrict__ v_acc)
{
  int d = blockIdx.x * 256 + threadIdx.x;
  int e0 = blockIdx.y * 64;
  float a = 0.f;
  for (int e = e0; e < e0 + 64; ++e) a += W[e * 1024 + d] * u_cur[e];
  atomicAdd(&v_acc[d], a);
}

__global__ void k_u(const float* __restrict__ W, const float* __restrict__ v_cur,
                    float* __restrict__ u_acc)
{
  int lg = threadIdx.x & 15, ei = threadIdx.x >> 4;
  int e = blockIdx.y * 16 + ei;
  int d0 = blockIdx.x * 512;
  float a = 0.f;
  for (int i = 0; i < 32; ++i) { int d = d0 + lg + 16 * i; a += W[e * 1024 + d] * v_cur[d]; }
#pragma unroll
  for (int m = 1; m < 16; m <<= 1) a += __shfl_xor(a, m);
  if (lg == 0) atomicAdd(&u_acc[e], a);
}

__global__ void k_norm(const float* __restrict__ acc, float* __restrict__ outv,
                       float* __restrict__ z1)
{
  __shared__ float red[16];
  int t = threadIdx.x;
  float x = acc[t];
  float ss = x * x;
#pragma unroll
  for (int m = 1; m < 64; m <<= 1) ss += __shfl_xor(ss, m);
  if ((t & 63) == 0) red[t >> 6] = ss;
  __syncthreads();
  if (t < 64) {
    float s = (t < 16) ? red[t] : 0.f;
#pragma unroll
    for (int m = 1; m < 16; m <<= 1) s += __shfl_xor(s, m);
    if (t == 0) red[0] = s;
  }
  __syncthreads();
  float nrm = sqrtf(red[0]) + 1e-8f;
  outv[t] = x / nrm;
  z1[t] = 0.f;
}

__global__ void k_sigma(const float* __restrict__ acc, float* __restrict__ scale)
{
  __shared__ float red[16];
  int t = threadIdx.x;
  float x = acc[t];
  float ss = x * x;
#pragma unroll
  for (int m = 1; m < 64; m <<= 1) ss += __shfl_xor(ss, m);
  if ((t & 63) == 0) red[t >> 6] = ss;
  __syncthreads();
  if (t < 64) {
    float s = (t < 16) ? red[t] : 0.f;
#pragma unroll
    for (int m = 1; m < 16; m <<= 1) s += __shfl_xor(s, m);
    if (t == 0) {
      float sigma = s / (sqrtf(s) + 1e-8f);
      scale[0] = 0.95f / (sigma + 1e-8f);
    }
  }
}

__global__ void k_scale(const float* __restrict__ W, const float* __restrict__ scale,
                        u16* __restrict__ wb, u16* __restrict__ wbT)
{
  int i = blockIdx.x * 256 + threadIdx.x;
  float v = W[i] * scale[0];
  u16 h = f2b(v);
  wb[i] = h;
  wbT[(i & 1023) * 1024 + (i >> 10)] = h;
}

__global__ void k_cvt(const float* __restrict__ in, u16* __restrict__ out, int n)
{
  int i = (blockIdx.x * 256 + threadIdx.x) * 4;
  if (i >= n) return;
  float4 v = *(const float4*)(in + i);
  ushort4 o;
  o.x = f2b(v.x); o.y = f2b(v.y); o.z = f2b(v.z); o.w = f2b(v.w);
  *(ushort4*)(out + i) = o;
}

// phase-1 c=1 init: l_1[k] = pre[k*32]
__global__ void k_linit(const u16* __restrict__ preb, u16* __restrict__ l)
{
  int i = blockIdx.x * 256 + threadIdx.x;
  int m = i >> 8;
  int c4 = (i & 255) * 4;
  const u16* src = preb + ((((m >> 3) << 5)) * 8 + (m & 7)) * 1024 + c4;
  *(ushort4*)(l + m * 1024 + c4) = *(const ushort4*)src;
}

// Lambda_1[s,b] = lC[chunk s*8, b] = lC row s*64 + b
__global__ void k_gather(const float* __restrict__ lC, float* __restrict__ lam0)
{
  int i = blockIdx.x * 256 + threadIdx.x;   // 64 blocks
  int r = i >> 8;
  int e4 = (i & 255) * 4;
  int src = ((r >> 3) << 6) + (r & 7);
  *(float4*)(lam0 + r * 1024 + e4) = *(const float4*)(lC + src * 1024 + e4);
}

extern "C" void kernel_launch(void* const* d_in, const int* in_sizes, int n_in,
                              void* d_out, int out_size, void* d_ws, size_t ws_size,
                              hipStream_t stream)
{
  (void)in_sizes; (void)n_in; (void)out_size; (void)ws_size;
  const float* x  = (const float*)d_in[0];   // [2048,8,1024]
  const float* h0 = (const float*)d_in[1];   // [8,1024]
  const float* Wx = (const float*)d_in[2];   // [1024,1024]
  const float* Wh = (const float*)d_in[3];   // [1024,1024]
  const float* bv = (const float*)d_in[4];   // [1024]
  const float* uv = (const float*)d_in[5];   // [1024]

  float* out0 = (float*)d_out;               // [2048,8,1024] h^2*sig(h)
  float* hall = out0 + 16777216;             // [2049,8,1024]

  char* ws = (char*)d_ws;
  u16*   pre_b = (u16*)(ws);                  // 32 MB  pre bf16 [2048*8,1024]
  u16*   wh_b  = (u16*)(ws + 33554432);       // 2 MB   Wh bf16
  u16*   whT_b = (u16*)(ws + 35651584);       // 2 MB   Wh^T (later Wh^128)
  u16*   sA    = (u16*)(ws + 37748736);       // 2 MB   final: Wh^32 (M2)
  u16*   sAT   = (u16*)(ws + 39845888);
  u16*   sB    = (u16*)(ws + 41943040);       // 2 MB   final: Wh^256 (M256)
  u16*   sBT   = (u16*)(ws + 44040192);
  float* lC    = (float*)(ws + 46137344);     // 2 MB fp32 [512,1024] chunk-finals
  u16*   lCT   = (u16*)(ws + 46137344);       // (bf16 T-scratch during squaring only)
  u16*   lb0   = (u16*)(ws + 48234496);       // 1 MB   state ping
  u16*   lb1   = (u16*)(ws + 49283072);       // 1 MB   state pong
  u16*   bnd_b = (u16*)(ws + 50331648);       // 1 MB   bf16 boundaries [512,1024]
  float* lam0  = (float*)(ws + 51380224);     // 256 KB Lambda ping
  float* lam1  = (float*)(ws + 51642368);     // 256 KB Lambda pong
  float* bndS  = (float*)(ws + 51904512);     // 256 KB bnd[s*8] fp32, rows s*8+b
  float* pc0   = (float*)(ws + 52166656);     // 256 KB phase2c ping
  float* pc1   = (float*)(ws + 52428800);     // 256 KB phase2c pong
  float* u_cur = (float*)(ws + 52690944);
  float* v_cur = u_cur + 1024;
  float* v_acc = u_cur + 2048;
  float* u_acc = u_cur + 3072;
  float* scale = u_cur + 4096;
  u16*   xb    = (u16*)d_out;                 // x bf16 staged in out0 (dead before phase 3)

  k_init<<<32, 256, 0, stream>>>(uv, h0, u_cur, v_acc, u_acc, hall, bndS, bnd_b);

  for (int it = 0; it < 3; ++it) {
    k_v<<<dim3(4, 16), 256, 0, stream>>>(Wh, u_cur, v_acc);
    k_norm<<<1, 1024, 0, stream>>>(v_acc, v_cur, u_acc);
    k_u<<<dim3(2, 64), 256, 0, stream>>>(Wh, v_cur, u_acc);
    if (it < 2) k_norm<<<1, 1024, 0, stream>>>(u_acc, u_cur, v_acc);
    else        k_sigma<<<1, 1024, 0, stream>>>(u_acc, scale);
  }
  k_scale<<<4096, 256, 0, stream>>>(Wh, scale, wh_b, whT_b);

  // Wh powers by repeated squaring (A*B^T form, carrying transposes)
  gemm64<2><<<dim3(16, 16), 256, 0, stream>>>(wh_b, whT_b, nullptr, nullptr, sA, sAT, nullptr, nullptr, 0);  // ^2
  gemm64<2><<<dim3(16, 16), 256, 0, stream>>>(sA, sAT, nullptr, nullptr, sB, sBT, nullptr, nullptr, 0);      // ^4
  gemm64<2><<<dim3(16, 16), 256, 0, stream>>>(sB, sBT, nullptr, nullptr, sA, sAT, nullptr, nullptr, 0);      // ^8
  gemm64<2><<<dim3(16, 16), 256, 0, stream>>>(sA, sAT, nullptr, nullptr, sB, sBT, nullptr, nullptr, 0);      // ^16
  gemm64<2><<<dim3(16, 16), 256, 0, stream>>>(sB, sBT, nullptr, nullptr, sA, sAT, nullptr, nullptr, 0);      // ^32 = M2 (sA)
  gemm64<2><<<dim3(16, 16), 256, 0, stream>>>(sA, sAT, nullptr, nullptr, sB, sBT, nullptr, nullptr, 0);      // ^64
  gemm64<2><<<dim3(16, 16), 256, 0, stream>>>(sB, sBT, nullptr, nullptr, whT_b, lCT, nullptr, nullptr, 0);   // ^128
  gemm64<2><<<dim3(16, 16), 256, 0, stream>>>(whT_b, lCT, nullptr, nullptr, sB, nullptr, nullptr, nullptr, 0); // ^256 = M256 (sB)

  // pre = x @ Wx^T + b  (Wx bf16 parked behind bnd_b region? -> use lb0+lb1 space: 2MB needed; use bnd_b)
  k_cvt<<<16384, 256, 0, stream>>>(x, xb, 16777216);
  k_cvt<<<1024, 256, 0, stream>>>(Wx, bnd_b, 1048576);   // bnd_b region free until phase 2
  gemm64<3><<<dim3(16, 256), 256, 0, stream>>>(xb, bnd_b, nullptr, bv, pre_b, nullptr, nullptr, nullptr, 0);

  // phase 1: local scans from zero, 64 chunks in parallel (M=512), 31 steps
  k_linit<<<512, 256, 0, stream>>>(pre_b, lb0);
  for (int c = 2; c <= 32; ++c) {
    u16* in  = (c & 1) ? lb1 : lb0;
    u16* out = (c & 1) ? lb0 : lb1;
    gemm64<0><<<dim3(16, 8), 256, 0, stream>>>(in, wh_b, pre_b, nullptr, out, nullptr,
                                               (c == 32) ? lC : nullptr, nullptr, c);
  }

  // phase 2a: Lambda chain within superchunks (7 steps, fp32 state, M2=Wh^32)
  k_gather<<<64, 256, 0, stream>>>(lC, lam0);
  for (int c = 2; c <= 8; ++c) {
    const float* in = (c & 1) ? lam1 : lam0;
    float* out = (c & 1) ? lam0 : lam1;
    matvec<64><<<dim3(64, 8), 256, 0, stream>>>(in, sA, lC, out, nullptr, c - 1, 0);
  }
  // Lambda_8 lives in lam1 (c=8 output parity)

  // phase 2b: superchunk boundary chain (7 steps, M256=Wh^256)
  // bndS rows s*8+b hold bnd[s*8]; also emit bf16 boundaries for chunks (s+1)*8
  for (int s = 0; s < 7; ++s)
    matvec<8><<<dim3(64, 1), 256, 0, stream>>>(bndS + s * 8192, sB, lam1 + s * 8192,
                                               bndS + (s + 1) * 8192,
                                               bnd_b + (size_t)(s + 1) * 65536, 0, 0);

  // phase 2c: recover intra-superchunk boundaries (7 steps, M2)
  for (int c = 1; c <= 7; ++c) {
    const float* in = (c == 1) ? bndS : ((c & 1) ? pc1 : pc0);
    float* out = (c & 1) ? pc0 : pc1;
    matvec<64><<<dim3(64, 8), 256, 0, stream>>>(in, sA, lC, out, bnd_b, c - 1, c);
  }

  // phase 3: true recurrence per chunk from boundaries; fused silu epilogue (32 steps)
  for (int c = 1; c <= 32; ++c) {
    const u16* in = (c == 1) ? bnd_b : ((c & 1) ? lb1 : lb0);
    u16* out = (c & 1) ? lb0 : lb1;
    gemm64<1><<<dim3(16, 8), 256, 0, stream>>>(in, wh_b, pre_b, nullptr, out, nullptr, hall, out0, c);
  }
}